// Round 7
// baseline (163.239 us; speedup 1.0000x reference)
//
#include <hip/hip_runtime.h>
#include <math.h>

// Problem constants
#define HW 4096
#define C 320
#define CX 768
#define L 77
#define NB 10
#define NH 8
#define HD 40
#define NINST 8
#define SCALE 0.15811388300841898f  // 1/sqrt(40)
#define PSTR 104                    // P LDS row stride (halves)
#define KSTR 48                     // K row stride (halves, 16B-aligned)
#define VSTR 104                    // V row stride (halves, 16B-aligned)
#define XSTR 328                    // X LDS row stride (halves)
#define KBH (80 * KSTR)             // 3840 halves per (b,h) K block
#define VBH (48 * VSTR)             // 4992 halves per (b,h) V block
#define KVCP 264                    // KV B-stage LDS row stride (halves)

// prep segmentation: KV(130) + mask(16) + pad-init(80) + Wq/Wo packs(50)
#define SEG_KV   130
#define MASK_U0  130
#define PAD_U0   146
#define WPK_U0   226
#define NPREP    276

typedef _Float16 half8v __attribute__((ext_vector_type(8)));
typedef _Float16 half4v __attribute__((ext_vector_type(4)));
typedef float f32x4 __attribute__((ext_vector_type(4)));

__device__ __forceinline__ float axis_profile(int o, float lo, float hi) {
    float num = 0.f, den = 0.f;
    int j0 = 8 * o - 4;
#pragma unroll
    for (int t = 0; t < 16; ++t) {
        int j = j0 + t;
        float wt = 1.0f - fabsf((float)t - 7.5f) * 0.125f;
        if (j >= 0 && j < 512) {
            den += wt;
            float fj = (float)j;
            if (fj >= lo && fj < hi) num += wt;
        }
    }
    return num / den;
}

__device__ __forceinline__ half8v cvt8(float4 a, float4 b) {
    half8v h = {(_Float16)a.x, (_Float16)a.y, (_Float16)a.z, (_Float16)a.w,
                (_Float16)b.x, (_Float16)b.y, (_Float16)b.z, (_Float16)b.w};
    return h;
}

// ---------------------------------------------------------------------------
// Dispatch 1: KV projection (staged-coalesced B, R4-verified) + mask +
// pad-init + Wq/Wo f16 transpose-packs. Segments independent; write sets
// pairwise disjoint. (Unchanged from R4/R6 — R4-proven.)
// ---------------------------------------------------------------------------
__global__ __launch_bounds__(256) void prep_kernel(
        const float* __restrict__ bboxes, const float* __restrict__ ehs,
        const float* __restrict__ Wq, const float* __restrict__ Wk,
        const float* __restrict__ Wv, const float* __restrict__ Wo,
        float* __restrict__ wPh, float* __restrict__ wSum,
        _Float16* __restrict__ WqT, _Float16* __restrict__ WoT,
        _Float16* __restrict__ VTg, _Float16* __restrict__ Khp) {
    __shared__ __align__(16) unsigned char psm[34048];  // Bs(33792) | tile+mask
    int bx = blockIdx.x, tid = threadIdx.x;

    if (bx < SEG_KV) {
        const int K = CX, M = NB * L;
        int lane = tid & 63, wave = tid >> 6;
        int m0 = (bx / 10) * 64 + wave * 16;
        int n0 = (bx % 10) * 64;
        int lr = lane & 15, kq = (lane >> 4) * 8;
        int arow = m0 + lr; if (arow >= M) arow = M - 1;
        const float* ap = ehs + (size_t)arow * K + kq;
        const float* W = (n0 < C) ? Wk : Wv;
        int colbase = (n0 < C) ? n0 : n0 - C;
        _Float16* Bs = (_Float16*)psm;   // [64][KVCP]
        f32x4 acc0 = {0.f,0.f,0.f,0.f}, acc1 = acc0, acc2 = acc0, acc3 = acc0;
        for (int c3 = 0; c3 < 3; ++c3) {
            int k0c = c3 * 256;
            __syncthreads();   // protect previous chunk's reads
            for (int i = tid; i < 64 * 256; i += 256) {
                int col = i & 63, k = i >> 6;
                Bs[col * KVCP + k] = (_Float16)W[(size_t)(k0c + k) * C + colbase + col];
            }
            __syncthreads();
#pragma unroll
            for (int k0 = 0; k0 < 256; k0 += 32) {
                float4 a0 = *(const float4*)(ap + k0c + k0);
                float4 a1 = *(const float4*)(ap + k0c + k0 + 4);
                half8v af = cvt8(a0, a1);
                half8v b0 = *(const half8v*)&Bs[(0 * 16 + lr) * KVCP + kq + k0];
                half8v b1 = *(const half8v*)&Bs[(1 * 16 + lr) * KVCP + kq + k0];
                half8v b2 = *(const half8v*)&Bs[(2 * 16 + lr) * KVCP + kq + k0];
                half8v b3 = *(const half8v*)&Bs[(3 * 16 + lr) * KVCP + kq + k0];
                acc0 = __builtin_amdgcn_mfma_f32_16x16x32_f16(af, b0, acc0, 0, 0, 0);
                acc1 = __builtin_amdgcn_mfma_f32_16x16x32_f16(af, b1, acc1, 0, 0, 0);
                acc2 = __builtin_amdgcn_mfma_f32_16x16x32_f16(af, b2, acc2, 0, 0, 0);
                acc3 = __builtin_amdgcn_mfma_f32_16x16x32_f16(af, b3, acc3, 0, 0, 0);
            }
        }
        int rb = m0 + ((lane >> 4) << 2);
        f32x4 accs[4] = {acc0, acc1, acc2, acc3};
#pragma unroll
        for (int t = 0; t < 4; ++t) {
            int col = n0 + t * 16 + lr;
#pragma unroll
            for (int r = 0; r < 4; ++r) {
                int row = rb + r;
                if (row < M) {
                    int bb = row / 77;
                    int key = row - bb * 77;
                    if (col < C) {
                        int h = col / HD, d = col - h * HD;
                        Khp[((size_t)(bb * 8 + h) * 80 + key) * KSTR + d] = (_Float16)accs[t][r];
                    } else {
                        int ch = col - C;
                        int h = ch / HD, d = ch - h * HD;
                        VTg[((size_t)(bb * 8 + h) * 48 + d) * VSTR + key] = (_Float16)accs[t][r];
                    }
                }
            }
        }
    } else if (bx < PAD_U0) {
        float* sw_s = (float*)psm;          // [8][64]
        float* sh_s = (float*)psm + 512;    // [8][4]
        int oyb = (bx - MASK_U0) * 4;
        for (int i = tid; i < NINST * 64; i += 256) {
            int n = i >> 6, ox = i & 63;
            float lo = floorf(512.f * bboxes[n * 4 + 0]);
            float hi = floorf(512.f * bboxes[n * 4 + 2]);
            sw_s[n * 64 + ox] = axis_profile(ox, lo, hi);
        }
        if (tid < NINST * 4) {
            int n = tid >> 2, oy = tid & 3;
            float lo = floorf(512.f * bboxes[n * 4 + 1]);
            float hi = floorf(512.f * bboxes[n * 4 + 3]);
            sh_s[n * 4 + oy] = axis_profile(oyb + oy, lo, hi);
        }
        __syncthreads();
        int oy = tid >> 6, ox = tid & 63;
        int hw = (oyb + oy) * 64 + ox;
        float sum = 0.1f;
        wPh[hw] = 0.1f;
#pragma unroll
        for (int n = 0; n < NINST; ++n) {
            float wv = 10.f * sh_s[n * 4 + oy] * sw_s[n * 64 + ox];
            wPh[(n + 1) * HW + hw] = wv;
            sum += wv;
        }
        wSum[hw] = sum;
    } else if (bx < WPK_U0) {
        int bh = bx - PAD_U0;
        _Float16* Vb = VTg + (size_t)bh * VBH;
        for (int i = tid; i < 832; i += 256) {
            int dd = i / 104, key = i - dd * 104;
            Vb[(size_t)(40 + dd) * VSTR + key] = (_Float16)((dd == 0 && key < 77) ? 1.f : 0.f);
        }
        for (int i = tid; i < 1080; i += 256) {
            int dd = i / 27, key = 77 + i - dd * 27;
            Vb[(size_t)dd * VSTR + key] = (_Float16)0.f;
        }
        _Float16* Kb = Khp + (size_t)bh * KBH;
        for (int i = tid; i < 144; i += 256) {
            int key = 77 + i / 48, dd = i - (i / 48) * 48;
            Kb[(size_t)key * KSTR + dd] = (_Float16)0.f;
        }
    } else {
        float (*tile)[65] = (float (*)[65])psm;
        int zz = bx - WPK_U0;
        int z = zz / 25, inner = zz - z * 25;
        int by = inner / 5, bx2 = inner - by * 5;
        const float* W = z ? Wo : Wq;
        _Float16* WT = z ? WoT : WqT;
        int kt = by * 64, nt = bx2 * 64;
#pragma unroll
        for (int p = 0; p < 16; ++p) {
            int idx = p * 256 + tid;
            int k = idx >> 6, n = idx & 63;
            tile[k][n] = W[(size_t)(kt + k) * C + nt + n];
        }
        __syncthreads();
#pragma unroll
        for (int p = 0; p < 16; ++p) {
            int idx = p * 256 + tid;
            int n = idx >> 6, k = idx & 63;
            WT[(size_t)(nt + n) * C + kt + k] = (_Float16)tile[k][n];
        }
    }
}

// ---------------------------------------------------------------------------
// Dispatch 2 (r7): fused attention + O-projection, batch-split x2 — CLEAN
// REBUILD of the r6 geometry from verified parts (r6 NaN post-mortem: the
// macro-expanded prefetch pipeline was the prime suspect and was a proven
// perf-null anyway (r5); dropped. `half` renamed hb; af1 zero-initialized).
// Block = 16 q-rows x 8 heads x 2 batch-halves (1024 thr, 16 waves);
// wave = (hb = wave>>3, head = wave&7); hb 0 -> batches {0,2,4,6,8},
// hb 1 -> {1,3,5,7,9}. Chain halves, waves/SIMD doubles (2->4).
// Cond output is linear in batches: hb-partials -> Xs bands rows 16..31 /
// 32..47; O-proj accumulates both A-fragments into one MFMA accumulator.
// Batch-loop body is the R4-verified in-loop-load form.
// ---------------------------------------------------------------------------
__global__ __launch_bounds__(1024) void attn_oproj(
        const float* __restrict__ hs,      // (2,HW,C) f32
        const _Float16* __restrict__ WqT,  // (320,320)
        const _Float16* __restrict__ Khp,  // (80,80,KSTR)
        const _Float16* __restrict__ VTg,  // (80,48,VSTR)
        const float* __restrict__ wPh,     // (9,HW)
        const float* __restrict__ wSum,    // (HW)
        const _Float16* __restrict__ WoT,  // (320,320)
        const float* __restrict__ bo,      // (320)
        float* __restrict__ Out) {         // (8192,320) f32
    __shared__ _Float16 smem[16 * 2 * 16 * PSTR + 48 * XSTR];  // 137,984 B
    _Float16* Xs = smem + 16 * 2 * 16 * PSTR;                  // [48][XSTR]

    const int tid = threadIdx.x;
    const int wave = tid >> 6, lane = tid & 63;
    const int head = wave & 7;
    const int hb = wave >> 3;            // batch-half: 0 -> even b, 1 -> odd b
    const int qrow0 = blockIdx.x * 16;
    const int c = lane & 15, quad = lane >> 4;
    _Float16* pl0 = smem + (size_t)(wave * 2) * 16 * PSTR;
    _Float16* pl1 = pl0 + 16 * PSTR;
    half8v zero8 = {(_Float16)0.f,(_Float16)0.f,(_Float16)0.f,(_Float16)0.f,
                    (_Float16)0.f,(_Float16)0.f,(_Float16)0.f,(_Float16)0.f};

    // zero P-buf cols 40..95 in BOTH wave-private buffers (Q pad + key pad)
#pragma unroll
    for (int i = 0; i < 4; ++i) {
        int idx = i * 64 + lane;
        if (idx < 224) {
            int buf = idx / 112;
            int rem = idx - buf * 112;
            int row = rem / 7, ch = rem - row * 7;
            _Float16* pb = buf ? pl1 : pl0;
            *(half8v*)&pb[row * PSTR + 40 + ch * 8] = zero8;
        }
    }

    // ---- Q^T projection: A = WqT rows (L2), B = raw f32 hs (in-reg cvt).
    // Duplicated across the two batch-halves (reads are L2-hits). ----
    {
        const float* bu = hs + (size_t)(qrow0 + c) * C + quad * 8;
        const float* bc = bu + (size_t)HW * C;
        f32x4 qa0[3] = {}, qa1[3] = {};
        for (int k0 = 0; k0 < C; k0 += 32) {
            float4 u0 = *(const float4*)(bu + k0);
            float4 u1 = *(const float4*)(bu + k0 + 4);
            float4 c0 = *(const float4*)(bc + k0);
            float4 c1 = *(const float4*)(bc + k0 + 4);
            half8v hu = cvt8(u0, u1);
            half8v hc = cvt8(c0, c1);
#pragma unroll
            for (int t = 0; t < 3; ++t) {
                const _Float16* ap = WqT + (size_t)(head * HD + t * 16 + c) * C + quad * 8 + k0;
                half8v af = *(const half8v*)ap;
                qa0[t] = __builtin_amdgcn_mfma_f32_16x16x32_f16(af, hu, qa0[t], 0, 0, 0);
                qa1[t] = __builtin_amdgcn_mfma_f32_16x16x32_f16(af, hc, qa1[t], 0, 0, 0);
            }
        }
#pragma unroll
        for (int t = 0; t < 3; ++t) {
            if (t < 2 || quad < 2) {
                half4v h0 = {(_Float16)(qa0[t][0] * SCALE), (_Float16)(qa0[t][1] * SCALE),
                             (_Float16)(qa0[t][2] * SCALE), (_Float16)(qa0[t][3] * SCALE)};
                half4v h1 = {(_Float16)(qa1[t][0] * SCALE), (_Float16)(qa1[t][1] * SCALE),
                             (_Float16)(qa1[t][2] * SCALE), (_Float16)(qa1[t][3] * SCALE)};
                *(half4v*)(pl0 + c * PSTR + t * 16 + quad * 4) = h0;
                *(half4v*)(pl1 + c * PSTR + t * 16 + quad * 4) = h1;
            }
        }
    }
    // intra-wave LDS RAW: in-order DS pipe + compiler waitcnt (verified)
    half8v qu0 = *(const half8v*)(pl0 + (size_t)c * PSTR + quad * 8);
    half8v qu1 = *(const half8v*)(pl0 + (size_t)c * PSTR + 32 + quad * 8);
    half8v qc0 = *(const half8v*)(pl1 + (size_t)c * PSTR + quad * 8);
    half8v qc1 = *(const half8v*)(pl1 + (size_t)c * PSTR + 32 + quad * 8);

    f32x4 oacc[3] = {};
    const int srcl = 32 + c;   // lane holding O^T row d=40 (denominator)

    // ---- batch loop: this wave-half's 5 batches (R4-verified body) ----
#pragma unroll
    for (int i = 0; i < 5; ++i) {
        int b = hb + 2 * i;
        const _Float16* Kb = Khp + (size_t)(b * 8 + head) * KBH;
        const _Float16* Vb = VTg + (size_t)(b * 8 + head) * VBH;
        half8v qb0 = b ? qc0 : qu0;
        half8v qb1 = b ? qc1 : qu1;
        float w = b ? wPh[(size_t)(b - 1) * HW + qrow0 + c] : 1.f;

        // QK^T: A = K rows (key). ka1 overrun (k=48..63) reads adjacent valid
        // memory; multiplied by zeroed Q pad cols (verified invariant).
        f32x4 s[5];
#pragma unroll
        for (int u = 0; u < 5; ++u) {
            half8v ka0 = *(const half8v*)&Kb[(u * 16 + c) * KSTR + quad * 8];
            half8v ka1 = *(const half8v*)&Kb[(u * 16 + c) * KSTR + 32 + quad * 8];
            f32x4 a = {0.f,0.f,0.f,0.f};
            a = __builtin_amdgcn_mfma_f32_16x16x32_f16(ka0, qb0, a, 0, 0, 0);
            a = __builtin_amdgcn_mfma_f32_16x16x32_f16(ka1, qb1, a, 0, 0, 0);
            s[u] = a;
        }

        // exp + P^T -> wave-private LDS (pl0 reused per batch; in-order DS)
#pragma unroll
        for (int u = 0; u < 5; ++u) {
            half4v h = {(_Float16)__expf(s[u][0]), (_Float16)__expf(s[u][1]),
                        (_Float16)__expf(s[u][2]), (_Float16)__expf(s[u][3])};
            *(half4v*)(pl0 + c * PSTR + u * 16 + quad * 4) = h;
        }
        half8v p0 = *(const half8v*)(pl0 + (size_t)c * PSTR + quad * 8);
        half8v p1 = *(const half8v*)(pl0 + (size_t)c * PSTR + 32 + quad * 8);
        half8v p2 = *(const half8v*)(pl0 + (size_t)c * PSTR + 64 + quad * 8);

        // PV: A = V^T rows (d)
        f32x4 ox[3];
#pragma unroll
        for (int t = 0; t < 3; ++t) {
            half8v va0 = *(const half8v*)&Vb[(t * 16 + c) * VSTR + quad * 8];
            half8v va1 = *(const half8v*)&Vb[(t * 16 + c) * VSTR + 32 + quad * 8];
            half8v va2 = *(const half8v*)&Vb[(t * 16 + c) * VSTR + 64 + quad * 8];
            f32x4 a = {0.f,0.f,0.f,0.f};
            a = __builtin_amdgcn_mfma_f32_16x16x32_f16(va0, p0, a, 0, 0, 0);
            a = __builtin_amdgcn_mfma_f32_16x16x32_f16(va1, p1, a, 0, 0, 0);
            a = __builtin_amdgcn_mfma_f32_16x16x32_f16(va2, p2, a, 0, 0, 0);
            ox[t] = a;
        }

        float l = __shfl(ox[2][0], srcl, 64);

        if (b == 0) {
            float rin = 1.0f / l;
#pragma unroll
            for (int t = 0; t < 3; ++t) {
                if (t < 2 || quad < 2) {
                    half4v h = {(_Float16)(ox[t][0] * rin), (_Float16)(ox[t][1] * rin),
                                (_Float16)(ox[t][2] * rin), (_Float16)(ox[t][3] * rin)};
                    *(half4v*)(Xs + (size_t)c * XSTR + head * HD + t * 16 + quad * 4) = h;
                }
            }
        } else {
            float rf = w / l;
#pragma unroll
            for (int t = 0; t < 3; ++t) {
                oacc[t][0] += ox[t][0] * rf;
                oacc[t][1] += ox[t][1] * rf;
                oacc[t][2] += ox[t][2] * rf;
                oacc[t][3] += ox[t][3] * rf;
            }
        }
    }

    // partial cond rows -> Xs band (hb 0: rows 16..31, hb 1: rows 32..47)
    {
        int xrow = (hb ? 32 : 16) + c;
#pragma unroll
        for (int t = 0; t < 3; ++t) {
            if (t < 2 || quad < 2) {
                half4v h = {(_Float16)oacc[t][0], (_Float16)oacc[t][1],
                            (_Float16)oacc[t][2], (_Float16)oacc[t][3]};
                *(half4v*)(Xs + (size_t)xrow * XSTR + head * HD + t * 16 + quad * 4) = h;
            }
        }
    }
    __syncthreads();   // X-tile complete

    // ---- O-projection by waves 0..7: mt = wave&1 (uncond/cond),
    // n-tiles (wave>>1)*5 .. +4. Cond sums BOTH half-bands (linear). ----
    if (hb == 0) {
        int mt = wave & 1;
        int np = wave >> 1;
        f32x4 acc[5] = {};
#pragma unroll
        for (int k0 = 0; k0 < C; k0 += 32) {
            half8v af0 = zero8, af1 = zero8;
            if (mt == 0) {
                af0 = *(const half8v*)&Xs[(size_t)c * XSTR + k0 + quad * 8];
            } else {
                af0 = *(const half8v*)&Xs[(size_t)(16 + c) * XSTR + k0 + quad * 8];
                af1 = *(const half8v*)&Xs[(size_t)(32 + c) * XSTR + k0 + quad * 8];
            }
#pragma unroll
            for (int tt = 0; tt < 5; ++tt) {
                const _Float16* bp = WoT + (size_t)(np * 80 + tt * 16 + c) * C + k0 + quad * 8;
                half8v bf = *(const half8v*)bp;
                acc[tt] = __builtin_amdgcn_mfma_f32_16x16x32_f16(af0, bf, acc[tt], 0, 0, 0);
                if (mt == 1)
                    acc[tt] = __builtin_amdgcn_mfma_f32_16x16x32_f16(af1, bf, acc[tt], 0, 0, 0);
            }
        }
#pragma unroll
        for (int tt = 0; tt < 5; ++tt) {
            int col = np * 80 + tt * 16 + c;
            float bv = bo[col];
#pragma unroll
            for (int r = 0; r < 4; ++r) {
                int rr = quad * 4 + r;
                float v = acc[tt][r];
                size_t row;
                if (mt == 0) {
                    v += bv;
                    row = (size_t)qrow0 + rr;
                } else {
                    float ws = wSum[qrow0 + rr];
                    v = (v + bv * ws) / (ws + 1e-6f);
                    row = (size_t)HW + qrow0 + rr;
                }
                Out[row * C + col] = v;
            }
        }
    }
}

// ---------------------------------------------------------------------------
// Launch: 2 dispatches.
// ---------------------------------------------------------------------------
extern "C" void kernel_launch(void* const* d_in, const int* in_sizes, int n_in,
                              void* d_out, int out_size, void* d_ws, size_t ws_size,
                              hipStream_t stream) {
    const float* hs   = (const float*)d_in[0];
    const float* ehs  = (const float*)d_in[1];
    const float* bbox = (const float*)d_in[2];
    const float* Wq   = (const float*)d_in[3];
    const float* Wk   = (const float*)d_in[4];
    const float* Wv   = (const float*)d_in[5];
    const float* Wo   = (const float*)d_in[6];
    const float* bo   = (const float*)d_in[7];
    float* out = (float*)d_out;

    float* wPh  = (float*)d_ws;                          // 9*4096 f32
    float* wSum = wPh + (size_t)9 * HW;                  // 4096 f32
    _Float16* WqT = (_Float16*)(wSum + HW);              // 320*320 f16
    _Float16* WoT = WqT + (size_t)C * C;                 // 320*320 f16
    _Float16* Khp = WoT + (size_t)C * C;                 // 80*80*KSTR f16
    _Float16* VTg = Khp + (size_t)80 * KBH;              // 80*48*VSTR f16

    prep_kernel<<<dim3(NPREP), 256, 0, stream>>>(bbox, ehs, Wq, Wk, Wv, Wo,
                                                 wPh, wSum, WqT, WoT, VTg, Khp);
    attn_oproj<<<dim3(HW / 16), 1024, 0, stream>>>(hs, WqT, Khp, VTg, wPh, wSum,
                                                   WoT, bo, out);
}

// Round 8
// 144.293 us; speedup vs baseline: 1.1313x; 1.1313x over previous
//
#include <hip/hip_runtime.h>
#include <math.h>

// Problem constants
#define HW 4096
#define C 320
#define CX 768
#define L 77
#define NB 10
#define NH 8
#define HD 40
#define NINST 8
#define SCALE 0.15811388300841898f  // 1/sqrt(40)
#define PSTR 104                    // P LDS row stride (halves)
#define KSTR 48                     // K row stride (halves, 16B-aligned)
#define VSTR 104                    // V row stride (halves, 16B-aligned)
#define XSTR 328                    // X LDS row stride (halves)
#define KBH (80 * KSTR)             // 3840 halves per (b,h) K block
#define VBH (48 * VSTR)             // 4992 halves per (b,h) V block

// prep segmentation (r8): KV first (starts early), then mask/pads/packs,
// then the 2560-block hs-cvt flood that keeps all CUs fed while the 130
// KV latency-chains drain (r7 post-mortem: 276-block prep = 1 blk/CU,
// 1 wave/SIMD, ~70us invisible under the attn top-5 envelope; R2's
// 3595-block prep with the same KV code stayed under 44us total).
#define SEG_KV   130
#define MASK_U0  130
#define PAD_U0   146
#define WPK_U0   226
#define CVT_U0   276
#define N_CVT1   (2 * HW * C / 4)   // 655360 float4s
#define NPREP    (CVT_U0 + N_CVT1 / 256)   // 276 + 2560 = 2836

typedef _Float16 half8v __attribute__((ext_vector_type(8)));
typedef _Float16 half4v __attribute__((ext_vector_type(4)));
typedef float f32x4 __attribute__((ext_vector_type(4)));

__device__ __forceinline__ float axis_profile(int o, float lo, float hi) {
    float num = 0.f, den = 0.f;
    int j0 = 8 * o - 4;
#pragma unroll
    for (int t = 0; t < 16; ++t) {
        int j = j0 + t;
        float wt = 1.0f - fabsf((float)t - 7.5f) * 0.125f;
        if (j >= 0 && j < 512) {
            den += wt;
            float fj = (float)j;
            if (fj >= lo && fj < hi) num += wt;
        }
    }
    return num / den;
}

__device__ __forceinline__ half8v cvt8(float4 a, float4 b) {
    half8v h = {(_Float16)a.x, (_Float16)a.y, (_Float16)a.z, (_Float16)a.w,
                (_Float16)b.x, (_Float16)b.y, (_Float16)b.z, (_Float16)b.w};
    return h;
}

// ---------------------------------------------------------------------------
// Dispatch 1: KV projection (R2-verified strided-scalar form) + mask +
// pad-init + Wq/Wo packs + hs f32->f16 cvt (TLP blanket). Segments
// independent; write sets pairwise disjoint.
// ---------------------------------------------------------------------------
__global__ __launch_bounds__(256) void prep_kernel(
        const float* __restrict__ bboxes, const float* __restrict__ hs,
        const float* __restrict__ ehs,
        const float* __restrict__ Wq, const float* __restrict__ Wk,
        const float* __restrict__ Wv, const float* __restrict__ Wo,
        float* __restrict__ wPh, float* __restrict__ wSum,
        _Float16* __restrict__ hsH,
        _Float16* __restrict__ WqT, _Float16* __restrict__ WoT,
        _Float16* __restrict__ VTg, _Float16* __restrict__ Khp) {
    __shared__ __align__(16) unsigned char psm[16900];  // pack tile / mask bufs
    int bx = blockIdx.x, tid = threadIdx.x;

    if (bx < SEG_KV) {
        // ---- K/V GEMM: A = f32 ehs rows (vector); B = Wk/Wv strided scalar
        // gathers (independent, pipelined; R2-verified fast at high grid
        // parallelism — the cvt flood provides the TLP blanket) ----
        const int K = CX, M = NB * L;
        int lane = tid & 63, wave = tid >> 6;
        int m0 = (bx / 10) * 64 + wave * 16;
        int n0 = (bx % 10) * 64;
        int lr = lane & 15, kq = (lane >> 4) * 8;
        int arow = m0 + lr; if (arow >= M) arow = M - 1;
        const float* ap = ehs + (size_t)arow * K + kq;
        const float* wp[4];
        int cols[4];
#pragma unroll
        for (int t = 0; t < 4; ++t) {
            int col = n0 + t * 16 + lr;
            cols[t] = col;
            wp[t] = (col < C) ? (Wk + col) : (Wv + (col - C));
        }
        f32x4 acc0 = {0.f,0.f,0.f,0.f}, acc1 = acc0, acc2 = acc0, acc3 = acc0;
        for (int k0 = 0; k0 < K; k0 += 32) {
            float4 a0 = *(const float4*)(ap + k0);
            float4 a1 = *(const float4*)(ap + k0 + 4);
            half8v af = cvt8(a0, a1);
            half8v bf0, bf1, bf2, bf3;
#pragma unroll
            for (int j = 0; j < 8; ++j) {
                size_t kk = (size_t)(k0 + kq + j) * C;
                bf0[j] = (_Float16)wp[0][kk];
                bf1[j] = (_Float16)wp[1][kk];
                bf2[j] = (_Float16)wp[2][kk];
                bf3[j] = (_Float16)wp[3][kk];
            }
            acc0 = __builtin_amdgcn_mfma_f32_16x16x32_f16(af, bf0, acc0, 0, 0, 0);
            acc1 = __builtin_amdgcn_mfma_f32_16x16x32_f16(af, bf1, acc1, 0, 0, 0);
            acc2 = __builtin_amdgcn_mfma_f32_16x16x32_f16(af, bf2, acc2, 0, 0, 0);
            acc3 = __builtin_amdgcn_mfma_f32_16x16x32_f16(af, bf3, acc3, 0, 0, 0);
        }
        int rb = m0 + ((lane >> 4) << 2);
        f32x4 accs[4] = {acc0, acc1, acc2, acc3};
#pragma unroll
        for (int t = 0; t < 4; ++t) {
            int col = cols[t];
#pragma unroll
            for (int r = 0; r < 4; ++r) {
                int row = rb + r;
                if (row < M) {
                    int bb = row / 77;
                    int key = row - bb * 77;
                    if (col < C) {
                        int h = col / HD, d = col - h * HD;
                        Khp[((size_t)(bb * 8 + h) * 80 + key) * KSTR + d] = (_Float16)accs[t][r];
                    } else {
                        int ch = col - C;
                        int h = ch / HD, d = ch - h * HD;
                        VTg[((size_t)(bb * 8 + h) * 48 + d) * VSTR + key] = (_Float16)accs[t][r];
                    }
                }
            }
        }
    } else if (bx < PAD_U0) {
        // ---- mask unit: wPh + wSum for 4 oy rows ----
        float* sw_s = (float*)psm;          // [8][64]
        float* sh_s = (float*)psm + 512;    // [8][4]
        int oyb = (bx - MASK_U0) * 4;
        for (int i = tid; i < NINST * 64; i += 256) {
            int n = i >> 6, ox = i & 63;
            float lo = floorf(512.f * bboxes[n * 4 + 0]);
            float hi = floorf(512.f * bboxes[n * 4 + 2]);
            sw_s[n * 64 + ox] = axis_profile(ox, lo, hi);
        }
        if (tid < NINST * 4) {
            int n = tid >> 2, oy = tid & 3;
            float lo = floorf(512.f * bboxes[n * 4 + 1]);
            float hi = floorf(512.f * bboxes[n * 4 + 3]);
            sh_s[n * 4 + oy] = axis_profile(oyb + oy, lo, hi);
        }
        __syncthreads();
        int oy = tid >> 6, ox = tid & 63;
        int hw = (oyb + oy) * 64 + ox;
        float sum = 0.1f;
        wPh[hw] = 0.1f;
#pragma unroll
        for (int n = 0; n < NINST; ++n) {
            float wv = 10.f * sh_s[n * 4 + oy] * sw_s[n * 64 + ox];
            wPh[(n + 1) * HW + hw] = wv;
            sum += wv;
        }
        wSum[hw] = sum;
    } else if (bx < WPK_U0) {
        // ---- pad-init for one (b,h): VTg d40..47 (ones at d=40,key<77),
        // VTg d<40 keys 77..103 = 0, Khp keys 77..79 = 0 ----
        int bh = bx - PAD_U0;
        _Float16* Vb = VTg + (size_t)bh * VBH;
        for (int i = tid; i < 832; i += 256) {
            int dd = i / 104, key = i - dd * 104;
            Vb[(size_t)(40 + dd) * VSTR + key] = (_Float16)((dd == 0 && key < 77) ? 1.f : 0.f);
        }
        for (int i = tid; i < 1080; i += 256) {
            int dd = i / 27, key = 77 + i - dd * 27;
            Vb[(size_t)dd * VSTR + key] = (_Float16)0.f;
        }
        _Float16* Kb = Khp + (size_t)bh * KBH;
        for (int i = tid; i < 144; i += 256) {
            int key = 77 + i / 48, dd = i - (i / 48) * 48;
            Kb[(size_t)key * KSTR + dd] = (_Float16)0.f;
        }
    } else if (bx < CVT_U0) {
        // ---- Wq / Wo transpose-pack to f16 (K = C = 320) ----
        float (*tile)[65] = (float (*)[65])psm;
        int zz = bx - WPK_U0;
        int z = zz / 25, inner = zz - z * 25;
        int by = inner / 5, bx2 = inner - by * 5;
        const float* W = z ? Wo : Wq;
        _Float16* WT = z ? WoT : WqT;
        int kt = by * 64, nt = bx2 * 64;
#pragma unroll
        for (int p = 0; p < 16; ++p) {
            int idx = p * 256 + tid;
            int k = idx >> 6, n = idx & 63;
            tile[k][n] = W[(size_t)(kt + k) * C + nt + n];
        }
        __syncthreads();
#pragma unroll
        for (int p = 0; p < 16; ++p) {
            int idx = p * 256 + tid;
            int n = idx >> 6, k = idx & 63;
            WT[(size_t)(nt + n) * C + kt + k] = (_Float16)tile[k][n];
        }
    } else {
        // ---- hs f32 -> f16 (attn Q-proj B operand) — the TLP blanket ----
        int i = (bx - CVT_U0) * 256 + tid;
        float4 v = ((const float4*)hs)[i];
        half4v h = {(_Float16)v.x, (_Float16)v.y, (_Float16)v.z, (_Float16)v.w};
        ((half4v*)hsH)[i] = h;
    }
}

// ---------------------------------------------------------------------------
// Dispatch 2: fused attention + O-projection (R4-verified geometry: 512 thr,
// 8 waves, wave = head, 16 q-rows/block; plain batch loop — R5 proved the
// source-pipeline is perf-null; R7 proved batch-split TLP is negative).
// Only change vs R4: Q-proj B operand reads f16 hsH (halved loads/FETCH).
// ---------------------------------------------------------------------------
__global__ __launch_bounds__(512, 1) void attn_oproj(
        const _Float16* __restrict__ hsH,  // (8192,320) f16
        const _Float16* __restrict__ WqT,  // (320,320)
        const _Float16* __restrict__ Khp,  // (80,80,KSTR)
        const _Float16* __restrict__ VTg,  // (80,48,VSTR)
        const float* __restrict__ wPh,     // (9,HW)
        const float* __restrict__ wSum,    // (HW)
        const _Float16* __restrict__ WoT,  // (320,320)
        const float* __restrict__ bo,      // (320)
        float* __restrict__ Out) {         // (8192,320) f32
    __shared__ _Float16 smem[NH * 2 * 16 * PSTR + 32 * XSTR];  // 74240 B
    _Float16* Xs = smem + NH * 2 * 16 * PSTR;                  // [32][XSTR]

    const int tid = threadIdx.x;
    const int wave = tid >> 6, lane = tid & 63;
    const int head = wave;
    const int qrow0 = blockIdx.x * 16;
    const int c = lane & 15, quad = lane >> 4;
    _Float16* pl0 = smem + (size_t)(wave * 2) * 16 * PSTR;
    _Float16* pl1 = pl0 + 16 * PSTR;
    half8v zero8 = {(_Float16)0.f,(_Float16)0.f,(_Float16)0.f,(_Float16)0.f,
                    (_Float16)0.f,(_Float16)0.f,(_Float16)0.f,(_Float16)0.f};

    // zero P-buf cols 40..95 (Q pad + P pad keys 80..95); wave-private
#pragma unroll
    for (int i = 0; i < 4; ++i) {
        int idx = i * 64 + lane;
        if (idx < 224) {
            int buf = idx / 112;
            int rem = idx - buf * 112;
            int row = rem / 7, ch = rem - row * 7;
            _Float16* pb = buf ? pl1 : pl0;
            *(half8v*)&pb[row * PSTR + 40 + ch * 8] = zero8;
        }
    }

    // ---- Q^T projection: A = WqT rows (L2), B = f16 hsH rows ----
    {
        const _Float16* bu = hsH + (size_t)(qrow0 + c) * C + quad * 8;
        const _Float16* bc = bu + (size_t)HW * C;
        f32x4 qa0[3] = {}, qa1[3] = {};
        for (int k0 = 0; k0 < C; k0 += 32) {
            half8v hu = *(const half8v*)(bu + k0);
            half8v hc = *(const half8v*)(bc + k0);
#pragma unroll
            for (int t = 0; t < 3; ++t) {
                const _Float16* ap = WqT + (size_t)(head * HD + t * 16 + c) * C + quad * 8 + k0;
                half8v af = *(const half8v*)ap;
                qa0[t] = __builtin_amdgcn_mfma_f32_16x16x32_f16(af, hu, qa0[t], 0, 0, 0);
                qa1[t] = __builtin_amdgcn_mfma_f32_16x16x32_f16(af, hc, qa1[t], 0, 0, 0);
            }
        }
#pragma unroll
        for (int t = 0; t < 3; ++t) {
            if (t < 2 || quad < 2) {
                half4v h0 = {(_Float16)(qa0[t][0] * SCALE), (_Float16)(qa0[t][1] * SCALE),
                             (_Float16)(qa0[t][2] * SCALE), (_Float16)(qa0[t][3] * SCALE)};
                half4v h1 = {(_Float16)(qa1[t][0] * SCALE), (_Float16)(qa1[t][1] * SCALE),
                             (_Float16)(qa1[t][2] * SCALE), (_Float16)(qa1[t][3] * SCALE)};
                *(half4v*)(pl0 + c * PSTR + t * 16 + quad * 4) = h0;
                *(half4v*)(pl1 + c * PSTR + t * 16 + quad * 4) = h1;
            }
        }
    }
    // intra-wave LDS RAW: in-order DS pipe + compiler waitcnt (verified)
    half8v qu0 = *(const half8v*)(pl0 + (size_t)c * PSTR + quad * 8);
    half8v qu1 = *(const half8v*)(pl0 + (size_t)c * PSTR + 32 + quad * 8);
    half8v qc0 = *(const half8v*)(pl1 + (size_t)c * PSTR + quad * 8);
    half8v qc1 = *(const half8v*)(pl1 + (size_t)c * PSTR + 32 + quad * 8);

    f32x4 oacc[3] = {};
    const int srcl = 32 + c;   // lane holding O^T row d=40 (denominator)

    // ---- batch loop (R4-verified body; fragments straight from L2) ----
    for (int b = 0; b < NB; ++b) {
        const _Float16* Kb = Khp + (size_t)(b * 8 + head) * KBH;
        const _Float16* Vb = VTg + (size_t)(b * 8 + head) * VBH;
        half8v qb0 = b ? qc0 : qu0;
        half8v qb1 = b ? qc1 : qu1;
        float w = b ? wPh[(size_t)(b - 1) * HW + qrow0 + c] : 1.f;

        // QK^T: A = K rows (key). ka1 overrun (k=48..63) reads adjacent valid
        // memory; multiplied by zeroed Q pad cols (verified invariant).
        f32x4 s[5];
#pragma unroll
        for (int u = 0; u < 5; ++u) {
            half8v ka0 = *(const half8v*)&Kb[(u * 16 + c) * KSTR + quad * 8];
            half8v ka1 = *(const half8v*)&Kb[(u * 16 + c) * KSTR + 32 + quad * 8];
            f32x4 a = {0.f,0.f,0.f,0.f};
            a = __builtin_amdgcn_mfma_f32_16x16x32_f16(ka0, qb0, a, 0, 0, 0);
            a = __builtin_amdgcn_mfma_f32_16x16x32_f16(ka1, qb1, a, 0, 0, 0);
            s[u] = a;
        }

        // exp + P^T -> wave-private LDS
#pragma unroll
        for (int u = 0; u < 5; ++u) {
            half4v h = {(_Float16)__expf(s[u][0]), (_Float16)__expf(s[u][1]),
                        (_Float16)__expf(s[u][2]), (_Float16)__expf(s[u][3])};
            *(half4v*)(pl0 + c * PSTR + u * 16 + quad * 4) = h;
        }
        half8v p0 = *(const half8v*)(pl0 + (size_t)c * PSTR + quad * 8);
        half8v p1 = *(const half8v*)(pl0 + (size_t)c * PSTR + 32 + quad * 8);
        half8v p2 = *(const half8v*)(pl0 + (size_t)c * PSTR + 64 + quad * 8);

        // PV: A = V^T rows (d)
        f32x4 ox[3];
#pragma unroll
        for (int t = 0; t < 3; ++t) {
            half8v va0 = *(const half8v*)&Vb[(t * 16 + c) * VSTR + quad * 8];
            half8v va1 = *(const half8v*)&Vb[(t * 16 + c) * VSTR + 32 + quad * 8];
            half8v va2 = *(const half8v*)&Vb[(t * 16 + c) * VSTR + 64 + quad * 8];
            f32x4 a = {0.f,0.f,0.f,0.f};
            a = __builtin_amdgcn_mfma_f32_16x16x32_f16(va0, p0, a, 0, 0, 0);
            a = __builtin_amdgcn_mfma_f32_16x16x32_f16(va1, p1, a, 0, 0, 0);
            a = __builtin_amdgcn_mfma_f32_16x16x32_f16(va2, p2, a, 0, 0, 0);
            ox[t] = a;
        }

        float l = __shfl(ox[2][0], srcl, 64);

        if (b == 0) {
            float rin = 1.0f / l;
#pragma unroll
            for (int t = 0; t < 3; ++t) {
                if (t < 2 || quad < 2) {
                    half4v h = {(_Float16)(ox[t][0] * rin), (_Float16)(ox[t][1] * rin),
                                (_Float16)(ox[t][2] * rin), (_Float16)(ox[t][3] * rin)};
                    *(half4v*)(Xs + (size_t)c * XSTR + head * HD + t * 16 + quad * 4) = h;
                }
            }
        } else {
            float rf = w / l;
#pragma unroll
            for (int t = 0; t < 3; ++t) {
                oacc[t][0] += ox[t][0] * rf;
                oacc[t][1] += ox[t][1] * rf;
                oacc[t][2] += ox[t][2] * rf;
                oacc[t][3] += ox[t][3] * rf;
            }
        }
    }

    // fused cond rows -> X-tile rows 16..31
#pragma unroll
    for (int t = 0; t < 3; ++t) {
        if (t < 2 || quad < 2) {
            half4v h = {(_Float16)oacc[t][0], (_Float16)oacc[t][1],
                        (_Float16)oacc[t][2], (_Float16)oacc[t][3]};
            *(half4v*)(Xs + (size_t)(16 + c) * XSTR + head * HD + t * 16 + quad * 4) = h;
        }
    }
    __syncthreads();   // the single cross-wave sync: X-tile complete

    // ---- O-projection of the block's 32 X rows (16 uncond + 16 cond) ----
    {
        int mt = wave & 1;
        int np = wave >> 1;
        f32x4 acc[5] = {};
#pragma unroll
        for (int k0 = 0; k0 < C; k0 += 32) {
            half8v af = *(const half8v*)&Xs[(size_t)(mt * 16 + c) * XSTR + k0 + quad * 8];
#pragma unroll
            for (int tt = 0; tt < 5; ++tt) {
                const _Float16* bp = WoT + (size_t)(np * 80 + tt * 16 + c) * C + k0 + quad * 8;
                half8v bf = *(const half8v*)bp;
                acc[tt] = __builtin_amdgcn_mfma_f32_16x16x32_f16(af, bf, acc[tt], 0, 0, 0);
            }
        }
#pragma unroll
        for (int tt = 0; tt < 5; ++tt) {
            int col = np * 80 + tt * 16 + c;
            float bv = bo[col];
#pragma unroll
            for (int r = 0; r < 4; ++r) {
                int rr = quad * 4 + r;
                float v = acc[tt][r];
                size_t row;
                if (mt == 0) {
                    v += bv;
                    row = (size_t)qrow0 + rr;
                } else {
                    float ws = wSum[qrow0 + rr];
                    v = (v + bv * ws) / (ws + 1e-6f);
                    row = (size_t)HW + qrow0 + rr;
                }
                Out[row * C + col] = v;
            }
        }
    }
}

// ---------------------------------------------------------------------------
// Launch: 2 dispatches.
// ---------------------------------------------------------------------------
extern "C" void kernel_launch(void* const* d_in, const int* in_sizes, int n_in,
                              void* d_out, int out_size, void* d_ws, size_t ws_size,
                              hipStream_t stream) {
    const float* hs   = (const float*)d_in[0];
    const float* ehs  = (const float*)d_in[1];
    const float* bbox = (const float*)d_in[2];
    const float* Wq   = (const float*)d_in[3];
    const float* Wk   = (const float*)d_in[4];
    const float* Wv   = (const float*)d_in[5];
    const float* Wo   = (const float*)d_in[6];
    const float* bo   = (const float*)d_in[7];
    float* out = (float*)d_out;

    float* wPh  = (float*)d_ws;                          // 9*4096 f32
    float* wSum = wPh + (size_t)9 * HW;                  // 4096 f32
    _Float16* WqT = (_Float16*)(wSum + HW);              // 320*320 f16
    _Float16* WoT = WqT + (size_t)C * C;                 // 320*320 f16
    _Float16* Khp = WoT + (size_t)C * C;                 // 80*80*KSTR f16
    _Float16* VTg = Khp + (size_t)80 * KBH;              // 80*48*VSTR f16
    _Float16* hsH = VTg + (size_t)80 * VBH;              // 8192*320 f16

    prep_kernel<<<dim3(NPREP), 256, 0, stream>>>(bbox, hs, ehs, Wq, Wk, Wv, Wo,
                                                 wPh, wSum, hsH, WqT, WoT, VTg, Khp);
    attn_oproj<<<dim3(HW / 16), 512, 0, stream>>>(hsH, WqT, Khp, VTg, wPh, wSum,
                                                  WoT, bo, out);
}